// Round 11
// baseline (444.379 us; speedup 1.0000x reference)
//
#include <hip/hip_runtime.h>

typedef short s8v __attribute__((ext_vector_type(8)));
typedef short s4v __attribute__((ext_vector_type(4)));
typedef float f4v __attribute__((ext_vector_type(4)));
typedef float f4 __attribute__((ext_vector_type(4)));

#define N_PIX 16384
#define NE    8192
#define EDIM  256
#define ZQ_ELEMS 4194304
#define MARGIN 4.5e-4f
#define NGRP 512           // 16 codes per pruning group
#define ZROW 264           // zt row stride in shorts (528 B, 16B-aligned, bank-balanced)

__device__ __forceinline__ float bf2f(unsigned short u) {
    union { unsigned int i; float f; } c; c.i = ((unsigned int)u) << 16; return c.f;
}
__device__ __forceinline__ unsigned short f2bf(float f) {
    unsigned int u = __float_as_uint(f);
    u = (u + 0x7fffu + ((u >> 16) & 1u)) >> 16;   // RNE
    return (unsigned short)u;
}
__device__ __forceinline__ unsigned short f2bf_down(float f) {  // round toward -inf
    unsigned int u = __float_as_uint(f);
    unsigned short b = (unsigned short)(u >> 16);
    if ((u & 0xFFFFu) && (u >> 31)) b += 1;
    return b;
}

// numpy pairwise_sum over 128 squared elements (exact replication: 8
// accumulators, fixed combine tree), f32 RN ops, no FMA contraction.
__device__ __forceinline__ float np_pw128sq(const float* a) {
    float r[8];
    #pragma unroll
    for (int j = 0; j < 8; ++j) r[j] = __fmul_rn(a[j], a[j]);
    for (int i = 8; i < 128; i += 8)
        #pragma unroll
        for (int j = 0; j < 8; ++j) r[j] = __fadd_rn(r[j], __fmul_rn(a[i + j], a[i + j]));
    return __fadd_rn(__fadd_rn(__fadd_rn(r[0], r[1]), __fadd_rn(r[2], r[3])),
                     __fadd_rn(__fadd_rn(r[4], r[5]), __fadd_rn(r[6], r[7])));
}

// K0: cb16 = bf16(cb); esum32[k] = np.sum(cb[k]*cb[k]) in exact np-f32
// pairwise semantics. WS-only writes.
__global__ __launch_bounds__(256) void vq_prep(const float* __restrict__ cb,
                                               unsigned short* __restrict__ cb16,
                                               float* __restrict__ esum32) {
    int t = threadIdx.x;
    int base = blockIdx.x * 64;
    const float* src = cb + (size_t)base * EDIM;
    unsigned short* dst = cb16 + (size_t)base * EDIM;
    for (int i = 0; i < 64; ++i) dst[i * EDIM + t] = f2bf(src[i * EDIM + t]);
    if (t < 64) {
        const float* a = cb + (size_t)(base + t) * EDIM;
        esum32[base + t] = __fadd_rn(np_pw128sq(a), np_pw128sq(a + 128));
    }
}

// K1: MFMA pruning, z-tile staged in LDS (fixes VGPR-remat: round-10 ran at
// VGPR=96 < the 128 needed for resident z-frags => compiler re-issued the
// scalar z loads every K-iteration; VALUBusy 19% matched that 16x tax).
// Block (512 thr) stages 64 px x 256 ch as bf16 into zt once (coalesced
// reads), K-loop reads fragments via ds_read_b128. A=codes, B=pixels =>
// D col=pixel, row=code; 16-code group-max = 3 local fmax + 2 shfl, store
// coalesced. Grid 512: block bx owns pixels (bx>>1)*64, code half (bx&1).
// gmin[g][pixel] parked in d_out's z_q chunk (overwritten by vq_emit).
__global__ __launch_bounds__(512, 4) void vq_phase1(const float* __restrict__ z,
                                                    const unsigned short* __restrict__ cb16,
                                                    unsigned short* __restrict__ gmin) {
    __shared__ unsigned short zt[64 * ZROW];   // 33,792 B
    const int t = threadIdx.x;
    const int wave = t >> 6, lane = t & 63;
    const int col = lane & 15, q = lane >> 4;
    const int mb = (blockIdx.x >> 1) * 64;
    const int chalf = blockIdx.x & 1;

    // Stage: thread t covers px = t&63, channel-quad cg = (t>>6) + pass*8.
    // Global reads coalesced (64 consecutive f32 per channel row).
    {
        int px = t & 63;
        int n = mb + px;
        const float* zb = z + ((size_t)(n >> 10) << 18) + (size_t)(n & 1023);
        #pragma unroll
        for (int pass = 0; pass < 8; ++pass) {
            int c = ((t >> 6) + pass * 8) * 4;
            s4v v;
            #pragma unroll
            for (int j = 0; j < 4; ++j) v[j] = (short)f2bf(zb[(size_t)(c + j) << 10]);
            *(s4v*)&zt[px * ZROW + c] = v;
        }
    }
    __syncthreads();

    const int kbase = chalf * 4096 + wave * 512;
    for (int it = 0; it < 16; ++it) {
        int n0 = kbase + it * 32;
        const unsigned short* bb = cb16 + (size_t)(n0 + col) * EDIM + q * 8;
        f4v zz = {0.f, 0.f, 0.f, 0.f};
        f4v acc[4][2];
        #pragma unroll
        for (int pt = 0; pt < 4; ++pt) { acc[pt][0] = zz; acc[pt][1] = zz; }
        #pragma unroll
        for (int c0 = 0; c0 < 8; ++c0) {
            s8v C0 = *(const s8v*)(bb + c0 * 32);             // codes n0+col (A operand)
            s8v C1 = *(const s8v*)(bb + 16 * EDIM + c0 * 32); // codes n0+16+col
            #pragma unroll
            for (int pt = 0; pt < 4; ++pt) {
                // B frag: B[n=col=pixel][k=q*8+j], c = c0*32+q*8+j — 16B LDS read
                s8v Zf = *(const s8v*)&zt[(pt * 16 + col) * ZROW + c0 * 32 + q * 8];
                acc[pt][0] = __builtin_amdgcn_mfma_f32_16x16x32_bf16(C0, Zf, acc[pt][0], 0, 0, 0);
                acc[pt][1] = __builtin_amdgcn_mfma_f32_16x16x32_bf16(C1, Zf, acc[pt][1], 0, 0, 0);
            }
        }
        // D: col=lane&15 (pixel), row=q*4+r (code within 16). Group-max:
        int gbase = chalf * 256 + wave * 32 + it * 2;
        #pragma unroll
        for (int pt = 0; pt < 4; ++pt) {
            #pragma unroll
            for (int s = 0; s < 2; ++s) {
                f4v a = acc[pt][s];
                float mx = fmaxf(fmaxf(a[0], a[1]), fmaxf(a[2], a[3]));
                mx = fmaxf(mx, __shfl_xor(mx, 16));
                mx = fmaxf(mx, __shfl_xor(mx, 32));
                if (q == 0)
                    gmin[(size_t)(gbase + s) * N_PIX + mb + pt * 16 + col] =
                        f2bf_down(-2.0f * mx);
            }
        }
    }
}

// K2: rescore candidate 16-code groups replicating np f32 semantics:
// d = f32(f32(zsum + esum[k]) - f32(2 * f32(dot64))), argmin with
// FIRST-INDEX tie-break. 4 waves/block, wave owns pixels 4w..4w+3.
// One group rescored by the full wave: 4 lanes per code row (coalesced
// 64 B per quad), 4 independent f64 accs, 2-shfl quad reduce, per-lane
// best + ONE deferred wave reduce per pixel.
__global__ __launch_bounds__(256) void vq_phase2(const float* __restrict__ z,
                                                 const float* __restrict__ cb,
                                                 const float* __restrict__ esum32,
                                                 const unsigned short* __restrict__ gmin,
                                                 unsigned int* __restrict__ idxw) {
    __shared__ float zt[16 * 260];
    __shared__ unsigned short gm[NGRP * 17];
    __shared__ float zs[16];
    int t = threadIdx.x;
    int wave = t >> 6, lane = t & 63;
    int p0 = blockIdx.x * 16;
    int bb = p0 >> 10, inner = p0 & 1023;

    #pragma unroll
    for (int i = 0; i < 16; ++i) {
        int c = i * 16 + (t >> 4), p = t & 15;
        zt[p * 260 + c] = z[((size_t)(bb * 256 + c) << 10) + inner + p];
    }
    #pragma unroll
    for (int i = 0; i < 32; ++i) {
        int g = i * 16 + (t >> 4), p = t & 15;
        gm[g * 17 + p] = gmin[(size_t)g * N_PIX + p0 + p];
    }
    __syncthreads();
    if (t < 16) {
        const float* a = zt + t * 260;
        zs[t] = __fadd_rn(np_pw128sq(a), np_pw128sq(a + 128));  // np zsum
    }
    __syncthreads();

    #pragma unroll
    for (int pp = 0; pp < 4; ++pp) {
        int p = wave * 4 + pp;
        float lmin = 3.0e38f;
        #pragma unroll
        for (int j = 0; j < 8; ++j) lmin = fminf(lmin, bf2f(gm[(lane * 8 + j) * 17 + p]));
        #pragma unroll
        for (int m = 1; m < 64; m <<= 1) lmin = fminf(lmin, __shfl_xor(lmin, m));
        float thr = lmin + MARGIN;
        float zsp = zs[p];

        float bd = 3.0e38f; int bk = 0x7FFFFFFF;
        for (int j = 0; j < 8; ++j) {
            unsigned long long mask = __ballot(bf2f(gm[(lane * 8 + j) * 17 + p]) <= thr);
            while (mask) {
                int lb = __builtin_ctzll(mask); mask &= mask - 1;
                int g = lb * 8 + j;
                int k = g * 16 + (lane >> 2);
                const f4* cr = (const f4*)(cb + (size_t)k * EDIM) + (lane & 3);
                const f4* zr = (const f4*)(zt + p * 260) + (lane & 3);
                double a0 = 0.0, a1 = 0.0, a2 = 0.0, a3 = 0.0;
                #pragma unroll
                for (int i = 0; i < 16; ++i) {
                    f4 x = zr[i * 4], y = cr[i * 4];
                    a0 = fma((double)x[0], (double)y[0], a0);
                    a1 = fma((double)x[1], (double)y[1], a1);
                    a2 = fma((double)x[2], (double)y[2], a2);
                    a3 = fma((double)x[3], (double)y[3], a3);
                }
                double s = (a0 + a1) + (a2 + a3);
                s += __shfl_xor(s, 1);
                s += __shfl_xor(s, 2);
                float E = (float)s;                                   // einsum f32 surrogate
                float d = __fsub_rn(__fadd_rn(zsp, esum32[k]), __fmul_rn(2.0f, E));
                if (d < bd || (d == bd && k < bk)) { bd = d; bk = k; }
            }
        }
        #pragma unroll
        for (int m = 1; m < 64; m <<= 1) {
            float od = __shfl_xor(bd, m); int ok = __shfl_xor(bk, m);
            if (od < bd || (od == bd && ok < bk)) { bd = od; bk = ok; }
        }
        if (lane == 0) idxw[p0 + p] = (unsigned int)bk;
    }
}

// K3: SOLE final writer of z_q (f32 chunk0, overwrites gmin scratch) and
// indices (f32 chunk2).
__global__ __launch_bounds__(256) void vq_emit(const float* __restrict__ cb,
                                               const float* __restrict__ z,
                                               const unsigned int* __restrict__ idxw,
                                               float* __restrict__ outf,
                                               float* __restrict__ lossw) {
    __shared__ float red[4];
    int t = threadIdx.x;
    int gtid = blockIdx.x * 256 + t;
    if (gtid < N_PIX) outf[ZQ_ELEMS + 1 + gtid] = (float)(idxw[gtid] & (NE - 1));

    float acc = 0.f;
    size_t base = (size_t)blockIdx.x * 16384;
    for (int i = 0; i < 64; ++i) {
        size_t o = base + (size_t)i * 256 + t;
        int b = (int)(o >> 18);
        int c = (int)((o >> 10) & 255);
        int p = (int)(o & 1023);
        int idx = (int)(idxw[b * 1024 + p] & (NE - 1));
        float qv = cb[(size_t)idx * EDIM + c];
        outf[o] = qv;
        float d = qv - z[o];
        acc = fmaf(d, d, acc);
    }
    #pragma unroll
    for (int off = 32; off > 0; off >>= 1) acc += __shfl_down(acc, off);
    if ((t & 63) == 0) red[t >> 6] = acc;
    __syncthreads();
    if (t == 0) atomicAdd(lossw, red[0] + red[1] + red[2] + red[3]);
}

// K4: SOLE writer of loss (f32 chunk1).
__global__ void vq_finalize(const float* __restrict__ lossw, float* __restrict__ loss_out) {
    loss_out[0] = 1.25f * lossw[0] * (1.0f / 4194304.0f);
}

extern "C" void kernel_launch(void* const* d_in, const int* in_sizes, int n_in,
                              void* d_out, int out_size, void* d_ws, size_t ws_size,
                              hipStream_t stream) {
    const float* z  = (const float*)d_in[0];   // f32 [16,256,32,32]
    const float* cb = (const float*)d_in[1];   // f32 [8192,256]
    float* outf = (float*)d_out;               // f32 [z_q | loss | indices]
    // gmin scratch (512 groups x 16384 px, u16 = 16.78 MB) lives in the z_q
    // chunk of d_out between phase1 and phase2; vq_emit overwrites it.
    unsigned short* gmin = (unsigned short*)d_out;

    char* w = (char*)d_ws;
    unsigned short* cb16   = (unsigned short*)w;               //  4,194,304 B
    float*          esum32 = (float*)(w + 4194304);            //     32,768 B
    unsigned int*   idxw   = (unsigned int*)(w + 4227072);     //     65,536 B
    float*          lossw  = (float*)(w + 4292608);            //          4 B

    if (ws_size < 4292612) return;  // diagnostic: all-zero out => ws too small

    hipMemsetAsync(lossw, 0, sizeof(float), stream);
    vq_prep    <<<NE / 64, 256, 0, stream>>>(cb, cb16, esum32);
    vq_phase1  <<<(N_PIX / 64) * 2, 512, 0, stream>>>(z, cb16, gmin);
    vq_phase2  <<<N_PIX / 16, 256, 0, stream>>>(z, cb, esum32, gmin, idxw);
    vq_emit    <<<256, 256, 0, stream>>>(cb, z, idxw, outf, lossw);
    vq_finalize<<<1, 1, 0, stream>>>(lossw, outf + ZQ_ELEMS);
}

// Round 12
// 326.775 us; speedup vs baseline: 1.3599x; 1.3599x over previous
//
#include <hip/hip_runtime.h>

typedef short s8v __attribute__((ext_vector_type(8)));
typedef short s4v __attribute__((ext_vector_type(4)));
typedef float f4v __attribute__((ext_vector_type(4)));
typedef float f4 __attribute__((ext_vector_type(4)));

#define N_PIX 16384
#define NE    8192
#define EDIM  256
#define ZQ_ELEMS 4194304
#define MARGIN 4.5e-4f
#define NGRP 512           // 16 codes per pruning group

__device__ __forceinline__ float bf2f(unsigned short u) {
    union { unsigned int i; float f; } c; c.i = ((unsigned int)u) << 16; return c.f;
}
__device__ __forceinline__ unsigned short f2bf(float f) {
    unsigned int u = __float_as_uint(f);
    u = (u + 0x7fffu + ((u >> 16) & 1u)) >> 16;   // RNE
    return (unsigned short)u;
}
__device__ __forceinline__ unsigned short f2bf_down(float f) {  // round toward -inf
    unsigned int u = __float_as_uint(f);
    unsigned short b = (unsigned short)(u >> 16);
    if ((u & 0xFFFFu) && (u >> 31)) b += 1;
    return b;
}

// numpy pairwise_sum over 128 squared elements (exact replication: 8
// accumulators, fixed combine tree), f32 RN ops, no FMA contraction.
__device__ __forceinline__ float np_pw128sq(const float* a) {
    float r[8];
    #pragma unroll
    for (int j = 0; j < 8; ++j) r[j] = __fmul_rn(a[j], a[j]);
    for (int i = 8; i < 128; i += 8)
        #pragma unroll
        for (int j = 0; j < 8; ++j) r[j] = __fadd_rn(r[j], __fmul_rn(a[i + j], a[i + j]));
    return __fadd_rn(__fadd_rn(__fadd_rn(r[0], r[1]), __fadd_rn(r[2], r[3])),
                     __fadd_rn(__fadd_rn(r[4], r[5]), __fadd_rn(r[6], r[7])));
}

// K0: cb16 = bf16(cb); esum32[k] = np.sum(cb[k]*cb[k]) in exact np-f32
// pairwise semantics. WS-only writes.
__global__ __launch_bounds__(256) void vq_prep(const float* __restrict__ cb,
                                               unsigned short* __restrict__ cb16,
                                               float* __restrict__ esum32) {
    int t = threadIdx.x;
    int base = blockIdx.x * 64;
    const float* src = cb + (size_t)base * EDIM;
    unsigned short* dst = cb16 + (size_t)base * EDIM;
    for (int i = 0; i < 64; ++i) dst[i * EDIM + t] = f2bf(src[i * EDIM + t]);
    if (t < 64) {
        const float* a = cb + (size_t)(base + t) * EDIM;
        esum32[base + t] = __fadd_rn(np_pw128sq(a), np_pw128sq(a + 128));
    }
}

// K0b: z16[n][c] = bf16(z NCHW) pixel-major transpose (8 MB). Makes phase1
// B-fragments single dense 16 B loads instead of 8 scalar 4KB-strided
// loads + cvt (the root cause of r10's remat tax and r11's cache collapse).
__global__ __launch_bounds__(256) void vq_z16(const float* __restrict__ z,
                                              unsigned short* __restrict__ z16) {
    __shared__ unsigned short zl[64 * 264];
    int t = threadIdx.x;
    int p0 = blockIdx.x * 64;
    int bb = p0 >> 10, inner = p0 & 1023;
    for (int i = 0; i < 64; ++i) {
        int c = i * 4 + (t >> 6), p = t & 63;
        zl[p * 264 + c] = f2bf(z[((size_t)(bb * 256 + c) << 10) + inner + p]);
    }
    __syncthreads();
    #pragma unroll
    for (int j = 0; j < 8; ++j) {   // full-row coalesced stores (512 B/row)
        int r = j * 8 + (t >> 5), cs = (t & 31) * 8;
        *(s8v*)&z16[(size_t)(p0 + r) * EDIM + cs] = *(const s8v*)&zl[r * 264 + cs];
    }
}

// K1: MFMA pruning. A=codes, B=pixels => D col=pixel, row=code; 16-code
// group-max = 3 local fmax + 2 shfl, coalesced store. Grid 512: block bx
// owns pixels (bx>>1)*64, code half (bx&1); wave owns 512 codes. Z-frags
// are dense 16 B loads from z16 (L1-hot 32 KB/block) — cheap whether the
// allocator keeps them resident or remats. No LDS (r11 showed LDS+fast
// issue collapses cb16 L2 residency: FETCH 30->573 MB). gmin[g][pixel]
// parked in d_out's z_q chunk (overwritten later by vq_emit).
__global__ __launch_bounds__(512, 2) void vq_phase1(const unsigned short* __restrict__ z16,
                                                    const unsigned short* __restrict__ cb16,
                                                    unsigned short* __restrict__ gmin) {
    const int t = threadIdx.x;
    const int wave = t >> 6, lane = t & 63;
    const int col = lane & 15, q = lane >> 4;
    const int mb = (blockIdx.x >> 1) * 64;
    const int chalf = blockIdx.x & 1;

    // z frags (B operand): B[n=col=pixel][k=q*8+j]; one b128 load each.
    s8v Z[4][8];
    #pragma unroll
    for (int pt = 0; pt < 4; ++pt) {
        const unsigned short* zr = z16 + (size_t)(mb + pt * 16 + col) * EDIM + q * 8;
        #pragma unroll
        for (int c0 = 0; c0 < 8; ++c0) Z[pt][c0] = *(const s8v*)(zr + c0 * 32);
    }

    const int kbase = chalf * 4096 + wave * 512;
    for (int it = 0; it < 16; ++it) {
        int n0 = kbase + it * 32;
        const unsigned short* bb = cb16 + (size_t)(n0 + col) * EDIM + q * 8;
        f4v zz = {0.f, 0.f, 0.f, 0.f};
        f4v acc[4][2];
        #pragma unroll
        for (int pt = 0; pt < 4; ++pt) { acc[pt][0] = zz; acc[pt][1] = zz; }
        #pragma unroll
        for (int c0 = 0; c0 < 8; ++c0) {
            s8v C0 = *(const s8v*)(bb + c0 * 32);             // codes n0+col (A operand)
            s8v C1 = *(const s8v*)(bb + 16 * EDIM + c0 * 32); // codes n0+16+col
            #pragma unroll
            for (int pt = 0; pt < 4; ++pt) {
                acc[pt][0] = __builtin_amdgcn_mfma_f32_16x16x32_bf16(C0, Z[pt][c0], acc[pt][0], 0, 0, 0);
                acc[pt][1] = __builtin_amdgcn_mfma_f32_16x16x32_bf16(C1, Z[pt][c0], acc[pt][1], 0, 0, 0);
            }
        }
        // D: col=lane&15 (pixel), row=q*4+r (code within 16). Group-max:
        int gbase = chalf * 256 + wave * 32 + it * 2;
        #pragma unroll
        for (int pt = 0; pt < 4; ++pt) {
            #pragma unroll
            for (int s = 0; s < 2; ++s) {
                f4v a = acc[pt][s];
                float mx = fmaxf(fmaxf(a[0], a[1]), fmaxf(a[2], a[3]));
                mx = fmaxf(mx, __shfl_xor(mx, 16));
                mx = fmaxf(mx, __shfl_xor(mx, 32));
                if (q == 0)
                    gmin[(size_t)(gbase + s) * N_PIX + mb + pt * 16 + col] =
                        f2bf_down(-2.0f * mx);
            }
        }
    }
}

// K2: rescore candidate 16-code groups replicating np f32 semantics:
// d = f32(f32(zsum + esum[k]) - f32(2 * f32(dot64))), argmin with
// FIRST-INDEX tie-break. 4 waves/block, wave owns pixels 4w..4w+3.
__global__ __launch_bounds__(256) void vq_phase2(const float* __restrict__ z,
                                                 const float* __restrict__ cb,
                                                 const float* __restrict__ esum32,
                                                 const unsigned short* __restrict__ gmin,
                                                 unsigned int* __restrict__ idxw) {
    __shared__ float zt[16 * 260];
    __shared__ unsigned short gm[NGRP * 17];
    __shared__ float zs[16];
    int t = threadIdx.x;
    int wave = t >> 6, lane = t & 63;
    int p0 = blockIdx.x * 16;
    int bb = p0 >> 10, inner = p0 & 1023;

    #pragma unroll
    for (int i = 0; i < 16; ++i) {
        int c = i * 16 + (t >> 4), p = t & 15;
        zt[p * 260 + c] = z[((size_t)(bb * 256 + c) << 10) + inner + p];
    }
    #pragma unroll
    for (int i = 0; i < 32; ++i) {
        int g = i * 16 + (t >> 4), p = t & 15;
        gm[g * 17 + p] = gmin[(size_t)g * N_PIX + p0 + p];
    }
    __syncthreads();
    if (t < 16) {
        const float* a = zt + t * 260;
        zs[t] = __fadd_rn(np_pw128sq(a), np_pw128sq(a + 128));  // np zsum
    }
    __syncthreads();

    #pragma unroll
    for (int pp = 0; pp < 4; ++pp) {
        int p = wave * 4 + pp;
        float lmin = 3.0e38f;
        #pragma unroll
        for (int j = 0; j < 8; ++j) lmin = fminf(lmin, bf2f(gm[(lane * 8 + j) * 17 + p]));
        #pragma unroll
        for (int m = 1; m < 64; m <<= 1) lmin = fminf(lmin, __shfl_xor(lmin, m));
        float thr = lmin + MARGIN;
        float zsp = zs[p];

        float bd = 3.0e38f; int bk = 0x7FFFFFFF;
        for (int j = 0; j < 8; ++j) {
            unsigned long long mask = __ballot(bf2f(gm[(lane * 8 + j) * 17 + p]) <= thr);
            while (mask) {
                int lb = __builtin_ctzll(mask); mask &= mask - 1;
                int g = lb * 8 + j;
                int k = g * 16 + (lane >> 2);
                const f4* cr = (const f4*)(cb + (size_t)k * EDIM) + (lane & 3);
                const f4* zr = (const f4*)(zt + p * 260) + (lane & 3);
                double a0 = 0.0, a1 = 0.0, a2 = 0.0, a3 = 0.0;
                #pragma unroll
                for (int i = 0; i < 16; ++i) {
                    f4 x = zr[i * 4], y = cr[i * 4];
                    a0 = fma((double)x[0], (double)y[0], a0);
                    a1 = fma((double)x[1], (double)y[1], a1);
                    a2 = fma((double)x[2], (double)y[2], a2);
                    a3 = fma((double)x[3], (double)y[3], a3);
                }
                double s = (a0 + a1) + (a2 + a3);
                s += __shfl_xor(s, 1);
                s += __shfl_xor(s, 2);
                float E = (float)s;                                   // einsum f32 surrogate
                float d = __fsub_rn(__fadd_rn(zsp, esum32[k]), __fmul_rn(2.0f, E));
                if (d < bd || (d == bd && k < bk)) { bd = d; bk = k; }
            }
        }
        #pragma unroll
        for (int m = 1; m < 64; m <<= 1) {
            float od = __shfl_xor(bd, m); int ok = __shfl_xor(bk, m);
            if (od < bd || (od == bd && ok < bk)) { bd = od; bk = ok; }
        }
        if (lane == 0) idxw[p0 + p] = (unsigned int)bk;
    }
}

// K3: SOLE final writer of z_q (f32 chunk0, overwrites gmin scratch) and
// indices (f32 chunk2).
__global__ __launch_bounds__(256) void vq_emit(const float* __restrict__ cb,
                                               const float* __restrict__ z,
                                               const unsigned int* __restrict__ idxw,
                                               float* __restrict__ outf,
                                               float* __restrict__ lossw) {
    __shared__ float red[4];
    int t = threadIdx.x;
    int gtid = blockIdx.x * 256 + t;
    if (gtid < N_PIX) outf[ZQ_ELEMS + 1 + gtid] = (float)(idxw[gtid] & (NE - 1));

    float acc = 0.f;
    size_t base = (size_t)blockIdx.x * 16384;
    for (int i = 0; i < 64; ++i) {
        size_t o = base + (size_t)i * 256 + t;
        int b = (int)(o >> 18);
        int c = (int)((o >> 10) & 255);
        int p = (int)(o & 1023);
        int idx = (int)(idxw[b * 1024 + p] & (NE - 1));
        float qv = cb[(size_t)idx * EDIM + c];
        outf[o] = qv;
        float d = qv - z[o];
        acc = fmaf(d, d, acc);
    }
    #pragma unroll
    for (int off = 32; off > 0; off >>= 1) acc += __shfl_down(acc, off);
    if ((t & 63) == 0) red[t >> 6] = acc;
    __syncthreads();
    if (t == 0) atomicAdd(lossw, red[0] + red[1] + red[2] + red[3]);
}

// K4: SOLE writer of loss (f32 chunk1).
__global__ void vq_finalize(const float* __restrict__ lossw, float* __restrict__ loss_out) {
    loss_out[0] = 1.25f * lossw[0] * (1.0f / 4194304.0f);
}

extern "C" void kernel_launch(void* const* d_in, const int* in_sizes, int n_in,
                              void* d_out, int out_size, void* d_ws, size_t ws_size,
                              hipStream_t stream) {
    const float* z  = (const float*)d_in[0];   // f32 [16,256,32,32]
    const float* cb = (const float*)d_in[1];   // f32 [8192,256]
    float* outf = (float*)d_out;               // f32 [z_q | loss | indices]
    // gmin scratch (512 groups x 16384 px, u16 = 16.78 MB) lives in the z_q
    // chunk of d_out between phase1 and phase2; vq_emit overwrites it.
    unsigned short* gmin = (unsigned short*)d_out;

    char* w = (char*)d_ws;
    unsigned short* cb16   = (unsigned short*)w;               //  4,194,304 B
    unsigned short* z16    = (unsigned short*)(w + 4194304);   //  8,388,608 B
    float*          esum32 = (float*)(w + 12582912);           //     32,768 B
    unsigned int*   idxw   = (unsigned int*)(w + 12615680);    //     65,536 B
    float*          lossw  = (float*)(w + 12681216);           //          4 B

    if (ws_size < 12681220) return;  // diagnostic: all-zero out => ws too small

    hipMemsetAsync(lossw, 0, sizeof(float), stream);
    vq_prep    <<<NE / 64, 256, 0, stream>>>(cb, cb16, esum32);
    vq_z16     <<<N_PIX / 64, 256, 0, stream>>>(z, z16);
    vq_phase1  <<<(N_PIX / 64) * 2, 512, 0, stream>>>(z16, cb16, gmin);
    vq_phase2  <<<N_PIX / 16, 256, 0, stream>>>(z, cb, esum32, gmin, idxw);
    vq_emit    <<<256, 256, 0, stream>>>(cb, z, idxw, outf, lossw);
    vq_finalize<<<1, 1, 0, stream>>>(lossw, outf + ZQ_ELEMS);
}